// Round 13
// baseline (1892.851 us; speedup 1.0000x reference)
//
#include <hip/hip_runtime.h>
#include <hip/hip_bf16.h>

typedef __attribute__((ext_vector_type(8))) short bf16x8;
typedef __attribute__((ext_vector_type(4))) float f32x4;

#define MFMA __builtin_amdgcn_mfma_f32_16x16x32_bf16

// ---------- helpers ----------
__device__ __forceinline__ short f2bf(float f) {
    union { __hip_bfloat16 h; short s; } u;
    u.h = __float2bfloat16(f);
    return u.s;
}

__device__ __forceinline__ void gld_lds16(const void* g, void* l) {
    auto gp = (const __attribute__((address_space(1))) void*)(g);
    auto lp = (__attribute__((address_space(3))) void*)(l);
    __builtin_amdgcn_global_load_lds(gp, lp, 16, 0, 0);
}

// ---------- fp32 [R][C] -> MFMA-fragment-tiled bf16 (no transpose) ----------
// tile (r16, c32): lane l holds (row=l&15, k=(l>>4)*8+j) at tile*1024 + l*16 + j*2
__global__ __launch_bounds__(64) void cvt_tile(const float* __restrict__ in,
                                               __hip_bfloat16* __restrict__ out, int C) {
    const int cd32 = C >> 5;
    const int tile = blockIdx.x;
    const int r16 = tile / cd32, c32 = tile - r16 * cd32;
    const int l = threadIdx.x;
    const int row = (r16 << 4) + (l & 15);
    const int c0 = (c32 << 5) + ((l >> 4) << 3);
    const float* src = in + (size_t)row * C + c0;
    short o[8];
#pragma unroll
    for (int j = 0; j < 8; ++j) o[j] = f2bf(src[j]);
    *(bf16x8*)((char*)out + (size_t)tile * 1024 + (l << 4)) = *(bf16x8*)o;
}

// ---------- fp32 W[K][N] -> fragment-tiled bf16 of W^T, LDS-staged coalesced ----------
__global__ __launch_bounds__(256) void tcvt256(const float* __restrict__ in,
                                               __hip_bfloat16* __restrict__ out,
                                               int N, int K) {
    __shared__ float tile[64][65];
    const int r0 = blockIdx.x << 6;  // K offset
    const int c0 = blockIdx.y << 6;  // N offset
    const int tid = threadIdx.x;
    const int row = tid >> 2, cq = tid & 3;
#pragma unroll
    for (int it = 0; it < 4; ++it) {
        int c4 = cq + (it << 2);
        float4 vv = *(const float4*)(in + (size_t)(r0 + row) * N + c0 + (c4 << 2));
        tile[row][(c4 << 2) + 0] = vv.x;
        tile[row][(c4 << 2) + 1] = vv.y;
        tile[row][(c4 << 2) + 2] = vv.z;
        tile[row][(c4 << 2) + 3] = vv.w;
    }
    __syncthreads();
    const int kd32 = K >> 5;
#pragma unroll
    for (int half = 0; half < 2; ++half) {
        int slot = tid + (half << 8);
        int ti = slot >> 6, l = slot & 63;
        int ci = ti & 3, ri = ti >> 2;
        short o[8];
#pragma unroll
        for (int j = 0; j < 8; ++j)
            o[j] = f2bf(tile[(ri << 5) + ((l >> 4) << 3) + j][(ci << 4) + (l & 15)]);
        size_t tidx = (size_t)((c0 >> 4) + ci) * kd32 + (r0 >> 5) + ri;
        *(bf16x8*)((char*)out + tidx * 1024 + (l << 4)) = *(bf16x8*)o;
    }
}

// ---------- MN-split GEMM (h0 + steps): 64x64 tile, 4 waves as 2x2 of 32x32 ----------
// Full K per wave (KD32 k32-steps). Per k-step each wave loads 2 A-frags +
// 2 B-frags (contiguous 1KB each) direct to named VGPRs; A shared by 2 waves,
// B shared by 2 waves -> second reader hits L1, halving unique L2 fill.
// 4 rotating slots, 3-deep prefetch, compiler-managed vmcnt. No LDS at all.
// MODE 0: h0 (bf16 fragment-tiled out).  MODE 1: step (relu + input proj).
template <int MODE, int KD32>
__global__ __launch_bounds__(256) void gemm_mn(const __hip_bfloat16* __restrict__ A,
                                               const __hip_bfloat16* __restrict__ B,
                                               void* __restrict__ outp,
                                               const float* __restrict__ v,
                                               const float* __restrict__ Wi, int t) {
    const int id = blockIdx.x;
    const int xcd = id & 7, j = id >> 3;
    const int bn = (xcd << 3) + (j & 7);   // XCD k owns bn in [8k,8k+8): W L2-resident
    const int bm = j >> 3;
    const int tid = threadIdx.x, wv = tid >> 6, lane = tid & 63;
    const int wr = wv >> 1, wc = wv & 1;

    constexpr size_t FSTR = (size_t)KD32 << 10;  // fragment-row stride (bytes)
    const char* pA = (const char*)A +
                     ((size_t)(((bm << 2) + (wr << 1)) * KD32) << 10) + (lane << 4);
    const char* pB = (const char*)B +
                     ((size_t)(((bn << 2) + (wc << 1)) * KD32) << 10) + (lane << 4);

    f32x4 acc00 = {}, acc01 = {}, acc10 = {}, acc11 = {};
    bf16x8 A00, A01, A10, A11, A20, A21, A30, A31;
    bf16x8 B00, B01, B10, B11, B20, B21, B30, B31;

#define LOADG(S, KI)                                  \
    do {                                              \
        const char* pa_ = pA + ((size_t)(KI) << 10);  \
        const char* pb_ = pB + ((size_t)(KI) << 10);  \
        A##S##0 = *(const bf16x8*)(pa_);              \
        A##S##1 = *(const bf16x8*)(pa_ + FSTR);       \
        B##S##0 = *(const bf16x8*)(pb_);              \
        B##S##1 = *(const bf16x8*)(pb_ + FSTR);       \
    } while (0)

#define COMPUTE(S)                                     \
    do {                                               \
        acc00 = MFMA(A##S##0, B##S##0, acc00, 0, 0, 0);\
        acc01 = MFMA(A##S##0, B##S##1, acc01, 0, 0, 0);\
        acc10 = MFMA(A##S##1, B##S##0, acc10, 0, 0, 0);\
        acc11 = MFMA(A##S##1, B##S##1, acc11, 0, 0, 0);\
    } while (0)

#define ITER(S, SP, DOISS, KI)                  \
    do {                                        \
        if (DOISS) LOADG(SP, (KI) + 3);         \
        __builtin_amdgcn_sched_barrier(0);      \
        COMPUTE(S);                             \
        __builtin_amdgcn_sched_barrier(0);      \
    } while (0)

    LOADG(0, 0);
    __builtin_amdgcn_sched_barrier(0);
    LOADG(1, 1);
    __builtin_amdgcn_sched_barrier(0);
    LOADG(2, 2);
    __builtin_amdgcn_sched_barrier(0);

    int s = 0;
    for (; s + 4 < KD32; s += 4) {
        ITER(0, 3, true, s + 0);
        ITER(1, 0, true, s + 1);
        ITER(2, 1, true, s + 2);
        ITER(3, 2, true, s + 3);
    }
    ITER(0, 3, true,  s + 0);  // prefetches k-tile KD32-1
    ITER(1, 0, false, s + 1);
    ITER(2, 1, false, s + 2);
    ITER(3, 2, false, s + 3);

#undef ITER
#undef COMPUTE
#undef LOADG

    float av[2][2][4];
#pragma unroll
    for (int q = 0; q < 4; ++q) {
        av[0][0][q] = acc00[q]; av[0][1][q] = acc01[q];
        av[1][0][q] = acc10[q]; av[1][1][q] = acc11[q];
    }

    // epilogue: wave (wr,wc) owns rows [bm*64+wr*32,+32) x cols [bn*64+wc*32,+32)
    const int rb = (bm << 6) + (wr << 5) + ((lane >> 4) << 2);
    const int cb = (bn << 6) + (wc << 5) + (lane & 15);
    char* O = (char*)outp;
#pragma unroll
    for (int f = 0; f < 2; ++f)
#pragma unroll
        for (int j = 0; j < 4; ++j) {
            int r = rb + (f << 4) + j;
            float v0 = 0.f, v1 = 0.f;
            if constexpr (MODE == 1) {
                v0 = v[(size_t)(r * 100 + t) * 2 + 0];
                v1 = v[(size_t)(r * 100 + t) * 2 + 1];
            }
#pragma unroll
            for (int g = 0; g < 2; ++g) {
                int c = cb + (g << 4);
                float val = av[f][g][j];
                if constexpr (MODE == 1) {
                    val = fmaxf(val + v0 * Wi[c] + v1 * Wi[4096 + c], 0.0f);
                }
                size_t off = ((size_t)(r >> 4) * 128 + (c >> 5)) * 1024 +
                             ((size_t)((r & 15) + (((c >> 3) & 3) << 4)) << 4) +
                             ((c & 7) << 1);
                *(short*)(O + off) = f2bf(val);
            }
        }
}

// ---------- decoder: 256x256 tile, 8 waves, B LDS-shared, A reg-direct (round 12) ----------
__global__ __launch_bounds__(512) void gemm_dec(const __hip_bfloat16* __restrict__ G,
                                                const __hip_bfloat16* __restrict__ Wdt,
                                                float* __restrict__ out) {
    __shared__ __align__(16) char lds[65536];  // 4 bufs x 16KB
    const int id = blockIdx.x;                 // 200 = 100 t x 2 nh
    const int t = id >> 1, nh = id & 1;
    const int tid = threadIdx.x, wv = tid >> 6, lane = tid & 63;

    const char* pA = (const char*)G + (size_t)t * 2097152 +
                     ((size_t)(wv << 1) << 17) + (lane << 4);
    const char* pB = (const char*)Wdt + ((size_t)(nh << 4) << 17) + (lane << 4);

    f32x4 acc0[16] = {};
    f32x4 acc1[16] = {};
    bf16x8 A00, A01, A10, A11, A20, A21, A30, A31;

#define STAGE(SLOT, KI)                                                  \
    do {                                                                 \
        char* d_ = lds + ((SLOT) << 14);                                 \
        const char* b_ = pB + (((size_t)(wv << 1)) << 17) +              \
                         ((size_t)(KI) << 10);                           \
        gld_lds16(b_, d_ + ((wv << 1) << 10));                           \
        gld_lds16(b_ + (1 << 17), d_ + (((wv << 1) + 1) << 10));         \
    } while (0)

#define LOADA(S, KI)                                                     \
    do {                                                                 \
        const char* a_ = pA + ((size_t)(KI) << 10);                      \
        A##S##0 = *(const bf16x8*)(a_);                                  \
        A##S##1 = *(const bf16x8*)(a_ + (1 << 17));                      \
    } while (0)

#define COMPUTE(S)                                                       \
    do {                                                                 \
        const char* bb_ = lds + ((S) << 14) + (lane << 4);               \
        _Pragma("unroll") for (int f = 0; f < 16; ++f) {                 \
            bf16x8 b_ = *(const bf16x8*)(bb_ + (f << 10));               \
            acc0[f] = MFMA(A##S##0, b_, acc0[f], 0, 0, 0);               \
            acc1[f] = MFMA(A##S##1, b_, acc1[f], 0, 0, 0);               \
        }                                                                \
    } while (0)

#define ITER(S, SP, VM, DOISS, KI)                                 \
    do {                                                           \
        asm volatile("s_waitcnt vmcnt(%0)" ::"i"(VM) : "memory");  \
        __builtin_amdgcn_s_barrier();                              \
        __builtin_amdgcn_sched_barrier(0);                         \
        if (DOISS) {                                               \
            STAGE(SP, (KI) + 3);                                   \
            LOADA(SP, (KI) + 3);                                   \
        }                                                          \
        __builtin_amdgcn_sched_barrier(0);                         \
        COMPUTE(S);                                                \
    } while (0)

    STAGE(0, 0); LOADA(0, 0);
    __builtin_amdgcn_sched_barrier(0);
    STAGE(1, 1); LOADA(1, 1);
    __builtin_amdgcn_sched_barrier(0);
    STAGE(2, 2); LOADA(2, 2);
    __builtin_amdgcn_sched_barrier(0);

    int s = 0;
    for (; s + 4 < 128; s += 4) {
        ITER(0, 3, 8, true, s + 0);
        ITER(1, 0, 8, true, s + 1);
        ITER(2, 1, 8, true, s + 2);
        ITER(3, 2, 8, true, s + 3);
    }
    ITER(0, 3, 8, true,  s + 0);
    ITER(1, 0, 8, false, s + 1);
    ITER(2, 1, 4, false, s + 2);
    ITER(3, 2, 0, false, s + 3);

#undef ITER
#undef COMPUTE
#undef LOADA
#undef STAGE

    const int rb = (wv << 5) + ((lane >> 4) << 2);
    const int cb = (nh << 8) + (lane & 15);
#pragma unroll
    for (int f = 0; f < 16; ++f) {
        const int c = cb + (f << 4);
#pragma unroll
        for (int j = 0; j < 4; ++j) {
            int b0 = rb + j;
            int b1 = rb + 16 + j;
            out[((size_t)b0 * 100 + t) * 512 + c] = acc0[f][j];
            out[((size_t)b1 * 100 + t) * 512 + c] = acc1[f][j];
        }
    }
}

// ---------- launch ----------
extern "C" void kernel_launch(void* const* d_in, const int* in_sizes, int n_in,
                              void* d_out, int out_size, void* d_ws, size_t ws_size,
                              hipStream_t stream) {
    const float* v     = (const float*)d_in[0];  // [256][100][2]
    const float* P0    = (const float*)d_in[1];  // [256][512]
    const float* W_enc = (const float*)d_in[2];  // [512][4096]
    const float* W_in  = (const float*)d_in[3];  // [2][4096]
    const float* W_rec = (const float*)d_in[4];  // [4096][4096]
    const float* W_dec = (const float*)d_in[5];  // [4096][512]
    float* out = (float*)d_out;                  // [256][100][512]

    char* ws = (char*)d_ws;
    __hip_bfloat16* Wrt = (__hip_bfloat16*)(ws + 0);          // W_rec^T tiled
    __hip_bfloat16* Wet = (__hip_bfloat16*)(ws + 33554432);   // W_enc^T tiled
    __hip_bfloat16* Wdt = (__hip_bfloat16*)(ws + 37748736);   // W_dec^T tiled
    __hip_bfloat16* P0t = (__hip_bfloat16*)(ws + 41943040);   // P0 tiled
    __hip_bfloat16* h0  = (__hip_bfloat16*)(ws + 42205184);   // h0 tiled
    __hip_bfloat16* G   = (__hip_bfloat16*)(ws + 44302336);   // 100 tiled slabs

    tcvt256<<<dim3(64, 64), 256, 0, stream>>>(W_rec, Wrt, 4096, 4096);
    tcvt256<<<dim3(8, 64), 256, 0, stream>>>(W_enc, Wet, 4096, 512);
    tcvt256<<<dim3(64, 8), 256, 0, stream>>>(W_dec, Wdt, 512, 4096);
    cvt_tile<<<256, 64, 0, stream>>>(P0, P0t, 512);

    // h0 = P0 @ W_enc   (KD32 = 16)
    gemm_mn<0, 16><<<256, 256, 0, stream>>>(P0t, Wet, (void*)h0, nullptr, nullptr, 0);

    // recurrent steps (KD32 = 128), MN-split 2x2 waves, L1-shared operands
    for (int t = 0; t < 100; ++t) {
        const __hip_bfloat16* hprev = (t == 0) ? h0 : (G + (size_t)(t - 1) * 1048576);
        gemm_mn<1, 128><<<256, 256, 0, stream>>>(hprev, Wrt,
                                                 (void*)(G + (size_t)t * 1048576), v, W_in, t);
    }

    // decoder: 256x256 tiles, 200 blocks, 8 waves, B via LDS
    gemm_dec<<<200, 512, 0, stream>>>(G, Wdt, out);
}

// Round 14
// 1658.958 us; speedup vs baseline: 1.1410x; 1.1410x over previous
//
#include <hip/hip_runtime.h>
#include <hip/hip_bf16.h>

typedef __attribute__((ext_vector_type(8))) short bf16x8;
typedef __attribute__((ext_vector_type(4))) float f32x4;

#define MFMA __builtin_amdgcn_mfma_f32_16x16x32_bf16

// ---------- helpers ----------
__device__ __forceinline__ short f2bf(float f) {
    union { __hip_bfloat16 h; short s; } u;
    u.h = __float2bfloat16(f);
    return u.s;
}

__device__ __forceinline__ void gld_lds16(const void* g, void* l) {
    auto gp = (const __attribute__((address_space(1))) void*)(g);
    auto lp = (__attribute__((address_space(3))) void*)(l);
    __builtin_amdgcn_global_load_lds(gp, lp, 16, 0, 0);
}

// ---------- fp32 [R][C] -> MFMA-fragment-tiled bf16 (no transpose) ----------
// tile (r16, c32): lane l holds (row=l&15, k=(l>>4)*8+j) at tile*1024 + l*16 + j*2
__global__ __launch_bounds__(64) void cvt_tile(const float* __restrict__ in,
                                               __hip_bfloat16* __restrict__ out, int C) {
    const int cd32 = C >> 5;
    const int tile = blockIdx.x;
    const int r16 = tile / cd32, c32 = tile - r16 * cd32;
    const int l = threadIdx.x;
    const int row = (r16 << 4) + (l & 15);
    const int c0 = (c32 << 5) + ((l >> 4) << 3);
    const float* src = in + (size_t)row * C + c0;
    short o[8];
#pragma unroll
    for (int j = 0; j < 8; ++j) o[j] = f2bf(src[j]);
    *(bf16x8*)((char*)out + (size_t)tile * 1024 + (l << 4)) = *(bf16x8*)o;
}

// ---------- fp32 W[K][N] -> fragment-tiled bf16 of W^T, LDS-staged coalesced ----------
__global__ __launch_bounds__(256) void tcvt256(const float* __restrict__ in,
                                               __hip_bfloat16* __restrict__ out,
                                               int N, int K) {
    __shared__ float tile[64][65];
    const int r0 = blockIdx.x << 6;  // K offset
    const int c0 = blockIdx.y << 6;  // N offset
    const int tid = threadIdx.x;
    const int row = tid >> 2, cq = tid & 3;
#pragma unroll
    for (int it = 0; it < 4; ++it) {
        int c4 = cq + (it << 2);
        float4 vv = *(const float4*)(in + (size_t)(r0 + row) * N + c0 + (c4 << 2));
        tile[row][(c4 << 2) + 0] = vv.x;
        tile[row][(c4 << 2) + 1] = vv.y;
        tile[row][(c4 << 2) + 2] = vv.z;
        tile[row][(c4 << 2) + 3] = vv.w;
    }
    __syncthreads();
    const int kd32 = K >> 5;
#pragma unroll
    for (int half = 0; half < 2; ++half) {
        int slot = tid + (half << 8);
        int ti = slot >> 6, l = slot & 63;
        int ci = ti & 3, ri = ti >> 2;
        short o[8];
#pragma unroll
        for (int j = 0; j < 8; ++j)
            o[j] = f2bf(tile[(ri << 5) + ((l >> 4) << 3) + j][(ci << 4) + (l & 15)]);
        size_t tidx = (size_t)((c0 >> 4) + ci) * kd32 + (r0 >> 5) + ri;
        *(bf16x8*)((char*)out + tidx * 1024 + (l << 4)) = *(bf16x8*)o;
    }
}

// ---------- per-wave K-split GEMM (h0 + steps): round-9 structure ----------
// MODE 0: h0 (bf16 fragment-tiled out).  MODE 1: step (relu + input proj).
// Output stores are NON-TEMPORAL: G_t is mostly consumed by OTHER XCDs next
// step (via L3 after kernel-end flush), so local-L2 allocation is pure
// pollution that evicts the step-invariant W_rec slab (4 MB == L2 size).
template <int MODE, int NW, int KC>
__global__ __launch_bounds__(NW * 64) void gemm_r(const __hip_bfloat16* __restrict__ A,
                                                  const __hip_bfloat16* __restrict__ B,
                                                  void* __restrict__ outp,
                                                  const float* __restrict__ v,
                                                  const float* __restrict__ Wi, int t) {
    constexpr int KD32 = KC * NW;  // K/32 total
    __shared__ __align__(16) char lds[NW * 16384];  // reduction only
    const int id = blockIdx.x;
    const int xcd = id & 7, j = id >> 3;
    const int bn = (xcd << 3) + (j & 7);
    const int bm = j >> 3;
    const int tid = threadIdx.x, wv = tid >> 6, lane = tid & 63;
    char* myl = lds + (wv << 14);
    const int kw0 = wv * KC;
    const int bm4 = bm << 2, bn4 = bn << 2;

    constexpr size_t FSTR = (size_t)KD32 << 10;
    const char* pA = (const char*)A + (((size_t)(bm4 * KD32 + kw0)) << 10) + (lane << 4);
    const char* pB = (const char*)B + (((size_t)(bn4 * KD32 + kw0)) << 10) + (lane << 4);

    f32x4 acc[4][4] = {};
    bf16x8 A00, A01, A02, A03, A10, A11, A12, A13,
           A20, A21, A22, A23, A30, A31, A32, A33;
    bf16x8 B00, B01, B02, B03, B10, B11, B12, B13,
           B20, B21, B22, B23, B30, B31, B32, B33;

#define LOADG(S, KI)                                       \
    do {                                                   \
        const char* pa_ = pA + ((size_t)(KI) << 10);       \
        const char* pb_ = pB + ((size_t)(KI) << 10);       \
        A##S##0 = *(const bf16x8*)(pa_);                   \
        A##S##1 = *(const bf16x8*)(pa_ + FSTR);            \
        A##S##2 = *(const bf16x8*)(pa_ + 2 * FSTR);        \
        A##S##3 = *(const bf16x8*)(pa_ + 3 * FSTR);        \
        B##S##0 = *(const bf16x8*)(pb_);                   \
        B##S##1 = *(const bf16x8*)(pb_ + FSTR);            \
        B##S##2 = *(const bf16x8*)(pb_ + 2 * FSTR);        \
        B##S##3 = *(const bf16x8*)(pb_ + 3 * FSTR);        \
    } while (0)

#define COMPUTE(S)                                             \
    do {                                                       \
        acc[0][0] = MFMA(A##S##0, B##S##0, acc[0][0], 0, 0, 0);\
        acc[0][1] = MFMA(A##S##0, B##S##1, acc[0][1], 0, 0, 0);\
        acc[0][2] = MFMA(A##S##0, B##S##2, acc[0][2], 0, 0, 0);\
        acc[0][3] = MFMA(A##S##0, B##S##3, acc[0][3], 0, 0, 0);\
        acc[1][0] = MFMA(A##S##1, B##S##0, acc[1][0], 0, 0, 0);\
        acc[1][1] = MFMA(A##S##1, B##S##1, acc[1][1], 0, 0, 0);\
        acc[1][2] = MFMA(A##S##1, B##S##2, acc[1][2], 0, 0, 0);\
        acc[1][3] = MFMA(A##S##1, B##S##3, acc[1][3], 0, 0, 0);\
        acc[2][0] = MFMA(A##S##2, B##S##0, acc[2][0], 0, 0, 0);\
        acc[2][1] = MFMA(A##S##2, B##S##1, acc[2][1], 0, 0, 0);\
        acc[2][2] = MFMA(A##S##2, B##S##2, acc[2][2], 0, 0, 0);\
        acc[2][3] = MFMA(A##S##2, B##S##3, acc[2][3], 0, 0, 0);\
        acc[3][0] = MFMA(A##S##3, B##S##0, acc[3][0], 0, 0, 0);\
        acc[3][1] = MFMA(A##S##3, B##S##1, acc[3][1], 0, 0, 0);\
        acc[3][2] = MFMA(A##S##3, B##S##2, acc[3][2], 0, 0, 0);\
        acc[3][3] = MFMA(A##S##3, B##S##3, acc[3][3], 0, 0, 0);\
    } while (0)

#define ITER(S, SP, DOISS, KI)                  \
    do {                                        \
        if (DOISS) LOADG(SP, (KI) + 3);         \
        __builtin_amdgcn_sched_barrier(0);      \
        COMPUTE(S);                             \
        __builtin_amdgcn_sched_barrier(0);      \
    } while (0)

    LOADG(0, 0);
    __builtin_amdgcn_sched_barrier(0);
    LOADG(1, 1);
    __builtin_amdgcn_sched_barrier(0);
    LOADG(2, 2);
    __builtin_amdgcn_sched_barrier(0);

    int s = 0;
    for (; s + 4 < KC; s += 4) {
        ITER(0, 3, true, s + 0);
        ITER(1, 0, true, s + 1);
        ITER(2, 1, true, s + 2);
        ITER(3, 2, true, s + 3);
    }
    ITER(0, 3, true,  s + 0);
    ITER(1, 0, false, s + 1);
    ITER(2, 1, false, s + 2);
    ITER(3, 2, false, s + 3);

#undef ITER
#undef COMPUTE
#undef LOADG

    // cross-wave K-reduction via LDS
#pragma unroll
    for (int f = 0; f < 4; ++f)
#pragma unroll
        for (int g = 0; g < 4; ++g)
            *(f32x4*)(myl + (((f << 2) + g) << 10) + (lane << 4)) = acc[f][g];
    __syncthreads();

    constexpr int FPW = 16 / NW;
    f32x4 fin[FPW];
#pragma unroll
    for (int q = 0; q < FPW; ++q) {
        const int fid = wv * FPW + q;
        f32x4 ssum = {};
#pragma unroll
        for (int w = 0; w < NW; ++w)
            ssum += *(const f32x4*)(lds + (w << 14) + (fid << 10) + (lane << 4));
        fin[q] = ssum;
    }

    char* O = (char*)outp;
#pragma unroll
    for (int q = 0; q < FPW; ++q) {
        const int fid = wv * FPW + q;
        const int fr = fid >> 2, g = fid & 3;
        const int rbase = (bm << 6) + (fr << 4) + ((lane >> 4) << 2);
        const int c = (bn << 6) + (g << 4) + (lane & 15);
#pragma unroll
        for (int j = 0; j < 4; ++j) {
            int r = rbase + j;
            float val = fin[q][j];
            if constexpr (MODE == 1) {
                float v0 = v[(size_t)(r * 100 + t) * 2 + 0];
                float v1 = v[(size_t)(r * 100 + t) * 2 + 1];
                val = fmaxf(val + v0 * Wi[c] + v1 * Wi[4096 + c], 0.0f);
            }
            size_t off = ((size_t)(r >> 4) * 128 + (c >> 5)) * 1024 +
                         ((size_t)((r & 15) + (((c >> 3) & 3) << 4)) << 4) +
                         ((c & 7) << 1);
            __builtin_nontemporal_store(f2bf(val), (short*)(O + off));
        }
    }
}

// ---------- decoder: 256x256 tile, 8 waves, B LDS-shared, A reg-direct ----------
// A (G) is streamed once -> NON-TEMPORAL loads (protect Wdt residency);
// out stores non-temporal (never re-read).
__global__ __launch_bounds__(512) void gemm_dec(const __hip_bfloat16* __restrict__ G,
                                                const __hip_bfloat16* __restrict__ Wdt,
                                                float* __restrict__ out) {
    __shared__ __align__(16) char lds[65536];  // 4 bufs x 16KB
    const int id = blockIdx.x;                 // 200 = 100 t x 2 nh
    const int t = id >> 1, nh = id & 1;
    const int tid = threadIdx.x, wv = tid >> 6, lane = tid & 63;

    const char* pA = (const char*)G + (size_t)t * 2097152 +
                     ((size_t)(wv << 1) << 17) + (lane << 4);
    const char* pB = (const char*)Wdt + ((size_t)(nh << 4) << 17) + (lane << 4);

    f32x4 acc0[16] = {};
    f32x4 acc1[16] = {};
    bf16x8 A00, A01, A10, A11, A20, A21, A30, A31;

#define STAGE(SLOT, KI)                                                  \
    do {                                                                 \
        char* d_ = lds + ((SLOT) << 14);                                 \
        const char* b_ = pB + (((size_t)(wv << 1)) << 17) +              \
                         ((size_t)(KI) << 10);                           \
        gld_lds16(b_, d_ + ((wv << 1) << 10));                           \
        gld_lds16(b_ + (1 << 17), d_ + (((wv << 1) + 1) << 10));         \
    } while (0)

#define LOADA(S, KI)                                                     \
    do {                                                                 \
        const char* a_ = pA + ((size_t)(KI) << 10);                      \
        A##S##0 = __builtin_nontemporal_load((const bf16x8*)(a_));       \
        A##S##1 = __builtin_nontemporal_load((const bf16x8*)(a_ + (1 << 17))); \
    } while (0)

#define COMPUTE(S)                                                       \
    do {                                                                 \
        const char* bb_ = lds + ((S) << 14) + (lane << 4);               \
        _Pragma("unroll") for (int f = 0; f < 16; ++f) {                 \
            bf16x8 b_ = *(const bf16x8*)(bb_ + (f << 10));               \
            acc0[f] = MFMA(A##S##0, b_, acc0[f], 0, 0, 0);               \
            acc1[f] = MFMA(A##S##1, b_, acc1[f], 0, 0, 0);               \
        }                                                                \
    } while (0)

#define ITER(S, SP, VM, DOISS, KI)                                 \
    do {                                                           \
        asm volatile("s_waitcnt vmcnt(%0)" ::"i"(VM) : "memory");  \
        __builtin_amdgcn_s_barrier();                              \
        __builtin_amdgcn_sched_barrier(0);                         \
        if (DOISS) {                                               \
            STAGE(SP, (KI) + 3);                                   \
            LOADA(SP, (KI) + 3);                                   \
        }                                                          \
        __builtin_amdgcn_sched_barrier(0);                         \
        COMPUTE(S);                                                \
    } while (0)

    STAGE(0, 0); LOADA(0, 0);
    __builtin_amdgcn_sched_barrier(0);
    STAGE(1, 1); LOADA(1, 1);
    __builtin_amdgcn_sched_barrier(0);
    STAGE(2, 2); LOADA(2, 2);
    __builtin_amdgcn_sched_barrier(0);

    int s = 0;
    for (; s + 4 < 128; s += 4) {
        ITER(0, 3, 8, true, s + 0);
        ITER(1, 0, 8, true, s + 1);
        ITER(2, 1, 8, true, s + 2);
        ITER(3, 2, 8, true, s + 3);
    }
    ITER(0, 3, 8, true,  s + 0);
    ITER(1, 0, 8, false, s + 1);
    ITER(2, 1, 4, false, s + 2);
    ITER(3, 2, 0, false, s + 3);

#undef ITER
#undef COMPUTE
#undef LOADA
#undef STAGE

    const int rb = (wv << 5) + ((lane >> 4) << 2);
    const int cb = (nh << 8) + (lane & 15);
#pragma unroll
    for (int f = 0; f < 16; ++f) {
        const int c = cb + (f << 4);
#pragma unroll
        for (int j = 0; j < 4; ++j) {
            int b0 = rb + j;
            int b1 = rb + 16 + j;
            __builtin_nontemporal_store(acc0[f][j], &out[((size_t)b0 * 100 + t) * 512 + c]);
            __builtin_nontemporal_store(acc1[f][j], &out[((size_t)b1 * 100 + t) * 512 + c]);
        }
    }
}

// ---------- launch ----------
extern "C" void kernel_launch(void* const* d_in, const int* in_sizes, int n_in,
                              void* d_out, int out_size, void* d_ws, size_t ws_size,
                              hipStream_t stream) {
    const float* v     = (const float*)d_in[0];  // [256][100][2]
    const float* P0    = (const float*)d_in[1];  // [256][512]
    const float* W_enc = (const float*)d_in[2];  // [512][4096]
    const float* W_in  = (const float*)d_in[3];  // [2][4096]
    const float* W_rec = (const float*)d_in[4];  // [4096][4096]
    const float* W_dec = (const float*)d_in[5];  // [4096][512]
    float* out = (float*)d_out;                  // [256][100][512]

    char* ws = (char*)d_ws;
    __hip_bfloat16* Wrt = (__hip_bfloat16*)(ws + 0);          // W_rec^T tiled
    __hip_bfloat16* Wet = (__hip_bfloat16*)(ws + 33554432);   // W_enc^T tiled
    __hip_bfloat16* Wdt = (__hip_bfloat16*)(ws + 37748736);   // W_dec^T tiled
    __hip_bfloat16* P0t = (__hip_bfloat16*)(ws + 41943040);   // P0 tiled
    __hip_bfloat16* h0  = (__hip_bfloat16*)(ws + 42205184);   // h0 tiled
    __hip_bfloat16* G   = (__hip_bfloat16*)(ws + 44302336);   // 100 tiled slabs

    tcvt256<<<dim3(64, 64), 256, 0, stream>>>(W_rec, Wrt, 4096, 4096);
    tcvt256<<<dim3(8, 64), 256, 0, stream>>>(W_enc, Wet, 4096, 512);
    tcvt256<<<dim3(64, 8), 256, 0, stream>>>(W_dec, Wdt, 512, 4096);
    cvt_tile<<<256, 64, 0, stream>>>(P0, P0t, 512);

    // h0 = P0 @ W_enc   (K=512: NW=4, KC=4)
    gemm_r<0, 4, 4><<<256, 256, 0, stream>>>(P0t, Wet, (void*)h0, nullptr, nullptr, 0);

    // recurrent steps (K=4096: NW=4, KC=32)
    for (int t = 0; t < 100; ++t) {
        const __hip_bfloat16* hprev = (t == 0) ? h0 : (G + (size_t)(t - 1) * 1048576);
        gemm_r<1, 4, 32><<<256, 256, 0, stream>>>(hprev, Wrt,
                                                  (void*)(G + (size_t)t * 1048576), v, W_in, t);
    }

    // decoder: 256x256 tiles, 200 blocks, 8 waves, B via LDS
    gemm_dec<<<200, 512, 0, stream>>>(G, Wdt, out);
}

// Round 15
// 1466.715 us; speedup vs baseline: 1.2905x; 1.1311x over previous
//
#include <hip/hip_runtime.h>
#include <hip/hip_bf16.h>

typedef __attribute__((ext_vector_type(8))) short bf16x8;
typedef __attribute__((ext_vector_type(4))) float f32x4;

#define MFMA __builtin_amdgcn_mfma_f32_16x16x32_bf16

// ---------- helpers ----------
__device__ __forceinline__ short f2bf(float f) {
    union { __hip_bfloat16 h; short s; } u;
    u.h = __float2bfloat16(f);
    return u.s;
}

__device__ __forceinline__ void gld_lds16(const void* g, void* l) {
    auto gp = (const __attribute__((address_space(1))) void*)(g);
    auto lp = (__attribute__((address_space(3))) void*)(l);
    __builtin_amdgcn_global_load_lds(gp, lp, 16, 0, 0);
}

// ---------- fp32 [R][C] -> MFMA-fragment-tiled bf16 (no transpose) ----------
// tile (r16, c32): lane l holds (row=l&15, k=(l>>4)*8+j) at tile*1024 + l*16 + j*2
__global__ __launch_bounds__(64) void cvt_tile(const float* __restrict__ in,
                                               __hip_bfloat16* __restrict__ out, int C) {
    const int cd32 = C >> 5;
    const int tile = blockIdx.x;
    const int r16 = tile / cd32, c32 = tile - r16 * cd32;
    const int l = threadIdx.x;
    const int row = (r16 << 4) + (l & 15);
    const int c0 = (c32 << 5) + ((l >> 4) << 3);
    const float* src = in + (size_t)row * C + c0;
    short o[8];
#pragma unroll
    for (int j = 0; j < 8; ++j) o[j] = f2bf(src[j]);
    *(bf16x8*)((char*)out + (size_t)tile * 1024 + (l << 4)) = *(bf16x8*)o;
}

// ---------- fp32 W[K][N] -> fragment-tiled bf16 of W^T, LDS-staged coalesced ----------
__global__ __launch_bounds__(256) void tcvt256(const float* __restrict__ in,
                                               __hip_bfloat16* __restrict__ out,
                                               int N, int K) {
    __shared__ float tile[64][65];
    const int r0 = blockIdx.x << 6;  // K offset
    const int c0 = blockIdx.y << 6;  // N offset
    const int tid = threadIdx.x;
    const int row = tid >> 2, cq = tid & 3;
#pragma unroll
    for (int it = 0; it < 4; ++it) {
        int c4 = cq + (it << 2);
        float4 vv = *(const float4*)(in + (size_t)(r0 + row) * N + c0 + (c4 << 2));
        tile[row][(c4 << 2) + 0] = vv.x;
        tile[row][(c4 << 2) + 1] = vv.y;
        tile[row][(c4 << 2) + 2] = vv.z;
        tile[row][(c4 << 2) + 3] = vv.w;
    }
    __syncthreads();
    const int kd32 = K >> 5;
#pragma unroll
    for (int half = 0; half < 2; ++half) {
        int slot = tid + (half << 8);
        int ti = slot >> 6, l = slot & 63;
        int ci = ti & 3, ri = ti >> 2;
        short o[8];
#pragma unroll
        for (int j = 0; j < 8; ++j)
            o[j] = f2bf(tile[(ri << 5) + ((l >> 4) << 3) + j][(ci << 4) + (l & 15)]);
        size_t tidx = (size_t)((c0 >> 4) + ci) * kd32 + (r0 >> 5) + ri;
        *(bf16x8*)((char*)out + tidx * 1024 + (l << 4)) = *(bf16x8*)o;
    }
}

// ---------- per-wave K-split GEMM (h0 + steps): round-9 structure, unchanged ----------
// MODE 0: h0 (bf16 fragment-tiled out).  MODE 1: step (relu + input proj).
template <int MODE, int NW, int KC>
__global__ __launch_bounds__(NW * 64) void gemm_r(const __hip_bfloat16* __restrict__ A,
                                                  const __hip_bfloat16* __restrict__ B,
                                                  void* __restrict__ outp,
                                                  const float* __restrict__ v,
                                                  const float* __restrict__ Wi, int t) {
    constexpr int KD32 = KC * NW;  // K/32 total
    __shared__ __align__(16) char lds[NW * 16384];  // reduction only
    const int id = blockIdx.x;
    const int xcd = id & 7, j = id >> 3;
    const int bn = (xcd << 3) + (j & 7);
    const int bm = j >> 3;
    const int tid = threadIdx.x, wv = tid >> 6, lane = tid & 63;
    char* myl = lds + (wv << 14);
    const int kw0 = wv * KC;
    const int bm4 = bm << 2, bn4 = bn << 2;

    constexpr size_t FSTR = (size_t)KD32 << 10;
    const char* pA = (const char*)A + (((size_t)(bm4 * KD32 + kw0)) << 10) + (lane << 4);
    const char* pB = (const char*)B + (((size_t)(bn4 * KD32 + kw0)) << 10) + (lane << 4);

    f32x4 acc[4][4] = {};
    bf16x8 A00, A01, A02, A03, A10, A11, A12, A13,
           A20, A21, A22, A23, A30, A31, A32, A33;
    bf16x8 B00, B01, B02, B03, B10, B11, B12, B13,
           B20, B21, B22, B23, B30, B31, B32, B33;

#define LOADG(S, KI)                                       \
    do {                                                   \
        const char* pa_ = pA + ((size_t)(KI) << 10);       \
        const char* pb_ = pB + ((size_t)(KI) << 10);       \
        A##S##0 = *(const bf16x8*)(pa_);                   \
        A##S##1 = *(const bf16x8*)(pa_ + FSTR);            \
        A##S##2 = *(const bf16x8*)(pa_ + 2 * FSTR);        \
        A##S##3 = *(const bf16x8*)(pa_ + 3 * FSTR);        \
        B##S##0 = *(const bf16x8*)(pb_);                   \
        B##S##1 = *(const bf16x8*)(pb_ + FSTR);            \
        B##S##2 = *(const bf16x8*)(pb_ + 2 * FSTR);        \
        B##S##3 = *(const bf16x8*)(pb_ + 3 * FSTR);        \
    } while (0)

#define COMPUTE(S)                                             \
    do {                                                       \
        acc[0][0] = MFMA(A##S##0, B##S##0, acc[0][0], 0, 0, 0);\
        acc[0][1] = MFMA(A##S##0, B##S##1, acc[0][1], 0, 0, 0);\
        acc[0][2] = MFMA(A##S##0, B##S##2, acc[0][2], 0, 0, 0);\
        acc[0][3] = MFMA(A##S##0, B##S##3, acc[0][3], 0, 0, 0);\
        acc[1][0] = MFMA(A##S##1, B##S##0, acc[1][0], 0, 0, 0);\
        acc[1][1] = MFMA(A##S##1, B##S##1, acc[1][1], 0, 0, 0);\
        acc[1][2] = MFMA(A##S##1, B##S##2, acc[1][2], 0, 0, 0);\
        acc[1][3] = MFMA(A##S##1, B##S##3, acc[1][3], 0, 0, 0);\
        acc[2][0] = MFMA(A##S##2, B##S##0, acc[2][0], 0, 0, 0);\
        acc[2][1] = MFMA(A##S##2, B##S##1, acc[2][1], 0, 0, 0);\
        acc[2][2] = MFMA(A##S##2, B##S##2, acc[2][2], 0, 0, 0);\
        acc[2][3] = MFMA(A##S##2, B##S##3, acc[2][3], 0, 0, 0);\
        acc[3][0] = MFMA(A##S##3, B##S##0, acc[3][0], 0, 0, 0);\
        acc[3][1] = MFMA(A##S##3, B##S##1, acc[3][1], 0, 0, 0);\
        acc[3][2] = MFMA(A##S##3, B##S##2, acc[3][2], 0, 0, 0);\
        acc[3][3] = MFMA(A##S##3, B##S##3, acc[3][3], 0, 0, 0);\
    } while (0)

#define ITER(S, SP, DOISS, KI)                  \
    do {                                        \
        if (DOISS) LOADG(SP, (KI) + 3);         \
        __builtin_amdgcn_sched_barrier(0);      \
        COMPUTE(S);                             \
        __builtin_amdgcn_sched_barrier(0);      \
    } while (0)

    LOADG(0, 0);
    __builtin_amdgcn_sched_barrier(0);
    LOADG(1, 1);
    __builtin_amdgcn_sched_barrier(0);
    LOADG(2, 2);
    __builtin_amdgcn_sched_barrier(0);

    int s = 0;
    for (; s + 4 < KC; s += 4) {
        ITER(0, 3, true, s + 0);
        ITER(1, 0, true, s + 1);
        ITER(2, 1, true, s + 2);
        ITER(3, 2, true, s + 3);
    }
    ITER(0, 3, true,  s + 0);
    ITER(1, 0, false, s + 1);
    ITER(2, 1, false, s + 2);
    ITER(3, 2, false, s + 3);

#undef ITER
#undef COMPUTE
#undef LOADG

    // cross-wave K-reduction via LDS
#pragma unroll
    for (int f = 0; f < 4; ++f)
#pragma unroll
        for (int g = 0; g < 4; ++g)
            *(f32x4*)(myl + (((f << 2) + g) << 10) + (lane << 4)) = acc[f][g];
    __syncthreads();

    constexpr int FPW = 16 / NW;
    f32x4 fin[FPW];
#pragma unroll
    for (int q = 0; q < FPW; ++q) {
        const int fid = wv * FPW + q;
        f32x4 ssum = {};
#pragma unroll
        for (int w = 0; w < NW; ++w)
            ssum += *(const f32x4*)(lds + (w << 14) + (fid << 10) + (lane << 4));
        fin[q] = ssum;
    }

    char* O = (char*)outp;
#pragma unroll
    for (int q = 0; q < FPW; ++q) {
        const int fid = wv * FPW + q;
        const int fr = fid >> 2, g = fid & 3;
        const int rbase = (bm << 6) + (fr << 4) + ((lane >> 4) << 2);
        const int c = (bn << 6) + (g << 4) + (lane & 15);
#pragma unroll
        for (int j = 0; j < 4; ++j) {
            int r = rbase + j;
            float val = fin[q][j];
            if constexpr (MODE == 1) {
                float v0 = v[(size_t)(r * 100 + t) * 2 + 0];
                float v1 = v[(size_t)(r * 100 + t) * 2 + 1];
                val = fmaxf(val + v0 * Wi[c] + v1 * Wi[4096 + c], 0.0f);
            }
            size_t off = ((size_t)(r >> 4) * 128 + (c >> 5)) * 1024 +
                         ((size_t)((r & 15) + (((c >> 3) & 3) << 4)) << 4) +
                         ((c & 7) << 1);
            *(short*)(O + off) = f2bf(val);
        }
    }
}

// ---------- decoder: 256x256 tile, 8 waves, B LDS-shared, A reg-direct (round 12) ----------
__global__ __launch_bounds__(512) void gemm_dec(const __hip_bfloat16* __restrict__ G,
                                                const __hip_bfloat16* __restrict__ Wdt,
                                                float* __restrict__ out) {
    __shared__ __align__(16) char lds[65536];  // 4 bufs x 16KB
    const int id = blockIdx.x;                 // 200 = 100 t x 2 nh
    const int t = id >> 1, nh = id & 1;
    const int tid = threadIdx.x, wv = tid >> 6, lane = tid & 63;

    const char* pA = (const char*)G + (size_t)t * 2097152 +
                     ((size_t)(wv << 1) << 17) + (lane << 4);
    const char* pB = (const char*)Wdt + ((size_t)(nh << 4) << 17) + (lane << 4);

    f32x4 acc0[16] = {};
    f32x4 acc1[16] = {};
    bf16x8 A00, A01, A10, A11, A20, A21, A30, A31;

#define STAGE(SLOT, KI)                                                  \
    do {                                                                 \
        char* d_ = lds + ((SLOT) << 14);                                 \
        const char* b_ = pB + (((size_t)(wv << 1)) << 17) +              \
                         ((size_t)(KI) << 10);                           \
        gld_lds16(b_, d_ + ((wv << 1) << 10));                           \
        gld_lds16(b_ + (1 << 17), d_ + (((wv << 1) + 1) << 10));         \
    } while (0)

#define LOADA(S, KI)                                                     \
    do {                                                                 \
        const char* a_ = pA + ((size_t)(KI) << 10);                      \
        A##S##0 = *(const bf16x8*)(a_);                                  \
        A##S##1 = *(const bf16x8*)(a_ + (1 << 17));                      \
    } while (0)

#define COMPUTE(S)                                                       \
    do {                                                                 \
        const char* bb_ = lds + ((S) << 14) + (lane << 4);               \
        _Pragma("unroll") for (int f = 0; f < 16; ++f) {                 \
            bf16x8 b_ = *(const bf16x8*)(bb_ + (f << 10));               \
            acc0[f] = MFMA(A##S##0, b_, acc0[f], 0, 0, 0);               \
            acc1[f] = MFMA(A##S##1, b_, acc1[f], 0, 0, 0);               \
        }                                                                \
    } while (0)

#define ITER(S, SP, VM, DOISS, KI)                                 \
    do {                                                           \
        asm volatile("s_waitcnt vmcnt(%0)" ::"i"(VM) : "memory");  \
        __builtin_amdgcn_s_barrier();                              \
        __builtin_amdgcn_sched_barrier(0);                         \
        if (DOISS) {                                               \
            STAGE(SP, (KI) + 3);                                   \
            LOADA(SP, (KI) + 3);                                   \
        }                                                          \
        __builtin_amdgcn_sched_barrier(0);                         \
        COMPUTE(S);                                                \
    } while (0)

    STAGE(0, 0); LOADA(0, 0);
    __builtin_amdgcn_sched_barrier(0);
    STAGE(1, 1); LOADA(1, 1);
    __builtin_amdgcn_sched_barrier(0);
    STAGE(2, 2); LOADA(2, 2);
    __builtin_amdgcn_sched_barrier(0);

    int s = 0;
    for (; s + 4 < 128; s += 4) {
        ITER(0, 3, 8, true, s + 0);
        ITER(1, 0, 8, true, s + 1);
        ITER(2, 1, 8, true, s + 2);
        ITER(3, 2, 8, true, s + 3);
    }
    ITER(0, 3, 8, true,  s + 0);
    ITER(1, 0, 8, false, s + 1);
    ITER(2, 1, 4, false, s + 2);
    ITER(3, 2, 0, false, s + 3);

#undef ITER
#undef COMPUTE
#undef LOADA
#undef STAGE

    const int rb = (wv << 5) + ((lane >> 4) << 2);
    const int cb = (nh << 8) + (lane & 15);
#pragma unroll
    for (int f = 0; f < 16; ++f) {
        const int c = cb + (f << 4);
#pragma unroll
        for (int j = 0; j < 4; ++j) {
            int b0 = rb + j;
            int b1 = rb + 16 + j;
            out[((size_t)b0 * 100 + t) * 512 + c] = acc0[f][j];
            out[((size_t)b1 * 100 + t) * 512 + c] = acc1[f][j];
        }
    }
}

// ---------- launch ----------
extern "C" void kernel_launch(void* const* d_in, const int* in_sizes, int n_in,
                              void* d_out, int out_size, void* d_ws, size_t ws_size,
                              hipStream_t stream) {
    const float* v     = (const float*)d_in[0];  // [256][100][2]
    const float* P0    = (const float*)d_in[1];  // [256][512]
    const float* W_enc = (const float*)d_in[2];  // [512][4096]
    const float* W_in  = (const float*)d_in[3];  // [2][4096]
    const float* W_rec = (const float*)d_in[4];  // [4096][4096]
    const float* W_dec = (const float*)d_in[5];  // [4096][512]
    float* out = (float*)d_out;                  // [256][100][512]

    char* ws = (char*)d_ws;
    __hip_bfloat16* Wrt = (__hip_bfloat16*)(ws + 0);          // W_rec^T tiled
    __hip_bfloat16* Wet = (__hip_bfloat16*)(ws + 33554432);   // W_enc^T tiled
    __hip_bfloat16* Wdt = (__hip_bfloat16*)(ws + 37748736);   // W_dec^T tiled
    __hip_bfloat16* P0t = (__hip_bfloat16*)(ws + 41943040);   // P0 tiled
    __hip_bfloat16* h0  = (__hip_bfloat16*)(ws + 42205184);   // h0 tiled
    __hip_bfloat16* G   = (__hip_bfloat16*)(ws + 44302336);   // 100 tiled slabs

    tcvt256<<<dim3(64, 64), 256, 0, stream>>>(W_rec, Wrt, 4096, 4096);
    tcvt256<<<dim3(8, 64), 256, 0, stream>>>(W_enc, Wet, 4096, 512);
    tcvt256<<<dim3(64, 8), 256, 0, stream>>>(W_dec, Wdt, 512, 4096);
    cvt_tile<<<256, 64, 0, stream>>>(P0, P0t, 512);

    // h0 = P0 @ W_enc   (K=512: NW=4, KC=4)
    gemm_r<0, 4, 4><<<256, 256, 0, stream>>>(P0t, Wet, (void*)h0, nullptr, nullptr, 0);

    // recurrent steps (K=4096: NW=4, KC=32)
    for (int t = 0; t < 100; ++t) {
        const __hip_bfloat16* hprev = (t == 0) ? h0 : (G + (size_t)(t - 1) * 1048576);
        gemm_r<1, 4, 32><<<256, 256, 0, stream>>>(hprev, Wrt,
                                                  (void*)(G + (size_t)t * 1048576), v, W_in, t);
    }

    // decoder: 256x256 tiles, 200 blocks, 8 waves, B via LDS
    gemm_dec<<<200, 512, 0, stream>>>(G, Wdt, out);
}